// Round 18
// baseline (1233.414 us; speedup 1.0000x reference)
//
#include <hip/hip_runtime.h>

// ---------------------------------------------------------------------------
// TemporalCfCEncoder: T=128, N=256, D=256, H=4 heads (hd=64), L=3 layers.
//  - GEMMs: 128x128 tile, A LDS-staged (BK=64, raw barriers), B direct from
//    global (weights L2-resident) -> half the staging cost, 18KB LDS.
//  - attention: MFMA, S^T = K@Q^T direct from global; O^T = V^T@P^T swizzled LDS
//  - residual streams seq/xb in bf16 (f32 accumulate, one rounding per write)
//  - CfC scan: frozen R11 config (fdot2, 768 thr, L2-streamed weights,
//    compiler-pipelined; best measured 189 us).
// ---------------------------------------------------------------------------

#define T_DIM 128
#define N_DIM 256
#define D_DIM 256
#define H_DIM 4
#define HD_DIM 64
#define L_DIM 3
#define TN (T_DIM * N_DIM)

typedef __bf16 bf16x8 __attribute__((ext_vector_type(8)));
typedef __bf16 bf16x4 __attribute__((ext_vector_type(4)));
typedef float f32x4 __attribute__((ext_vector_type(4)));
typedef _Float16 f16x2 __attribute__((ext_vector_type(2)));

// LDS-only barrier: order ds ops across the WG without draining vmcnt.
#define LDS_BAR()                                            \
  do {                                                       \
    asm volatile("s_waitcnt lgkmcnt(0)" ::: "memory");       \
    __builtin_amdgcn_s_barrier();                            \
    __builtin_amdgcn_sched_barrier(0);                       \
  } while (0)

__device__ inline float wave_reduce_sum(float v) {
#pragma unroll
  for (int off = 32; off > 0; off >>= 1) v += __shfl_xor(v, off);
  return v;
}

__device__ inline float bf_to_f(unsigned short u) {
  return __uint_as_float((unsigned int)u << 16);
}

// ---------------- LN: one wave per row of 256 -> bf16 out ------------------
template <typename TI>
__global__ __launch_bounds__(256) void ln_kernel(const TI* __restrict__ x,
                                                 const float* __restrict__ sc,
                                                 const float* __restrict__ bi,
                                                 __bf16* __restrict__ y) {
  const int wid = threadIdx.x >> 6;
  const int lane = threadIdx.x & 63;
  const size_t row = (size_t)blockIdx.x * 4 + wid;
  float xv[4];
  if constexpr (__is_same(TI, float)) {
    const float4 v = *(const float4*)(x + row * D_DIM + lane * 4);
    xv[0] = v.x; xv[1] = v.y; xv[2] = v.z; xv[3] = v.w;
  } else {
    const bf16x4 v = *(const bf16x4*)(x + row * D_DIM + lane * 4);
#pragma unroll
    for (int i = 0; i < 4; ++i) xv[i] = (float)v[i];
  }
  float s = xv[0] + xv[1] + xv[2] + xv[3];
  float ss = xv[0] * xv[0] + xv[1] * xv[1] + xv[2] * xv[2] + xv[3] * xv[3];
  s = wave_reduce_sum(s);
  ss = wave_reduce_sum(ss);
  const float mean = s * (1.f / D_DIM);
  const float var = ss * (1.f / D_DIM) - mean * mean;
  const float r = rsqrtf(var + 1e-5f);
  const float4 scv = *(const float4*)(sc + lane * 4);
  const float4 biv = *(const float4*)(bi + lane * 4);
  bf16x4 ov;
  ov[0] = (__bf16)((xv[0] - mean) * r * scv.x + biv.x);
  ov[1] = (__bf16)((xv[1] - mean) * r * scv.y + biv.y);
  ov[2] = (__bf16)((xv[2] - mean) * r * scv.z + biv.z);
  ov[3] = (__bf16)((xv[3] - mean) * r * scv.w + biv.w);
  *(bf16x4*)(y + row * D_DIM + lane * 4) = ov;
}

// ---------------- Tiled GEMM: out = A[M,K] @ W[Nout,K]^T + bias (+epi) -----
// A staged in LDS (raw barriers, load-ahead); B read DIRECT from global
// (weights are L2-resident, <=384KB). EPI: 0=bias, 1=bias+residual, 2=SiLU.
// OBF: bf16/f32 out. RBF: residual is bf16 (1) or f32 (0).
template <int EPI, int OBF, int RBF>
__global__ __launch_bounds__(256) void gemm_tiled(const __bf16* __restrict__ A,
                                                  const __bf16* __restrict__ W,
                                                  const float* __restrict__ bias,
                                                  const void* __restrict__ R,
                                                  void* __restrict__ outv,
                                                  int M, int Nout, int K) {
  __shared__ __bf16 a_lds[128][72];
  const int tid = threadIdx.x;
  const int w = tid >> 6, l = tid & 63;
  const int lr = l & 15, kg = l >> 4;
  const int wm = (w & 1) * 64, wn = (w >> 1) * 64;
  const int m0 = blockIdx.x * 128, n0 = blockIdx.y * 128;
  const int srow = tid >> 1, scol = (tid & 1) * 32;
  const __bf16* ag = A + (size_t)(m0 + srow) * K + scol;

  bf16x8 av[4];
#pragma unroll
  for (int c = 0; c < 4; ++c) av[c] = *(const bf16x8*)(ag + c * 8);

  f32x4 acc[4][4] = {};
  for (int k0 = 0; k0 < K; k0 += 64) {
    LDS_BAR();  // all waves finished reading LDS of previous k-step
#pragma unroll
    for (int c = 0; c < 4; ++c) *(bf16x8*)&a_lds[srow][scol + c * 8] = av[c];
    if (k0 + 64 < K) {
#pragma unroll
      for (int c = 0; c < 4; ++c) av[c] = *(const bf16x8*)(ag + k0 + 64 + c * 8);
    }
    LDS_BAR();  // staging visible; next-step A loads remain in flight
#pragma unroll
    for (int ks = 0; ks < 2; ++ks) {
      bf16x8 af[4], bf[4];
#pragma unroll
      for (int mt = 0; mt < 4; ++mt)
        af[mt] = *(const bf16x8*)&a_lds[wm + mt * 16 + lr][ks * 32 + kg * 8];
#pragma unroll
      for (int nt = 0; nt < 4; ++nt)
        bf[nt] = *(const bf16x8*)(W + (size_t)(n0 + wn + nt * 16 + lr) * K + k0 + ks * 32 +
                                  kg * 8);
#pragma unroll
      for (int mt = 0; mt < 4; ++mt)
#pragma unroll
        for (int nt = 0; nt < 4; ++nt)
          acc[mt][nt] =
              __builtin_amdgcn_mfma_f32_16x16x32_bf16(af[mt], bf[nt], acc[mt][nt], 0, 0, 0);
    }
  }
  // epilogue: D[row=kg*4+j][col=lr] per 16x16 tile
#pragma unroll
  for (int nt = 0; nt < 4; ++nt) {
    const int col = n0 + wn + nt * 16 + lr;
    const float bvs = bias[col];
#pragma unroll
    for (int mt = 0; mt < 4; ++mt) {
#pragma unroll
      for (int j = 0; j < 4; ++j) {
        const int row = m0 + wm + mt * 16 + kg * 4 + j;
        float v = acc[mt][nt][j] + bvs;
        const size_t oi = (size_t)row * Nout + col;
        if (EPI == 1)
          v += RBF ? bf_to_f(((const unsigned short*)R)[oi]) : ((const float*)R)[oi];
        if (EPI == 2) v = v * (1.f / (1.f + __expf(-v)));
        if (OBF)
          ((__bf16*)outv)[oi] = (__bf16)v;
        else
          ((float*)outv)[oi] = v;
      }
    }
  }
}

// ---------------- Attention (MFMA): one WG per (t, head), 4 waves ----------
__global__ __launch_bounds__(256, 2) void attn_mfma(const __bf16* __restrict__ qkv,
                                                    __bf16* __restrict__ o) {
  const int t = blockIdx.x, h = blockIdx.y;
  const int tid = threadIdx.x;
  const int w = tid >> 6, l = tid & 63;
  const int lr = l & 15, kg = l >> 4;

  __shared__ __bf16 vt_lds[64 * 256];    // V^T [c][n], XOR-swizzled, 32KB
  __shared__ __bf16 p_lds[4][16 * 256];  // per-wave P [q][n], swizzled, 32KB

  {
    const __bf16* vrow = qkv + ((size_t)(t * N_DIM + tid)) * 768 + 512 + h * HD_DIM;
#pragma unroll
    for (int c8 = 0; c8 < 64; c8 += 8) {
      bf16x8 v = *(const bf16x8*)(vrow + c8);
#pragma unroll
      for (int i = 0; i < 8; ++i) {
        const int c = c8 + i;
        const int byte = (c * 512 + tid * 2) ^ ((c & 7) << 4);
        *(__bf16*)((char*)vt_lds + byte) = v[i];
      }
    }
  }
  __syncthreads();

  const __bf16* kbase = qkv + (size_t)t * N_DIM * 768 + 256 + h * HD_DIM;
  const __bf16* qbase = qkv + (size_t)t * N_DIM * 768 + h * HD_DIM;
  char* pw = (char*)&p_lds[w][0];

  for (int qt = 0; qt < 4; ++qt) {
    const int q0 = w * 64 + qt * 16;
    const bf16x8 qf0 = *(const bf16x8*)(qbase + (size_t)(q0 + lr) * 768 + kg * 8);
    const bf16x8 qf1 = *(const bf16x8*)(qbase + (size_t)(q0 + lr) * 768 + 32 + kg * 8);
    f32x4 acc[16];
#pragma unroll
    for (int nt = 0; nt < 16; ++nt) {
      const bf16x8 a0 = *(const bf16x8*)(kbase + (size_t)(nt * 16 + lr) * 768 + kg * 8);
      const bf16x8 a1 = *(const bf16x8*)(kbase + (size_t)(nt * 16 + lr) * 768 + 32 + kg * 8);
      f32x4 s = {};
      s = __builtin_amdgcn_mfma_f32_16x16x32_bf16(a0, qf0, s, 0, 0, 0);
      s = __builtin_amdgcn_mfma_f32_16x16x32_bf16(a1, qf1, s, 0, 0, 0);
      acc[nt] = s;
    }
    float mx = -3.0e38f;
#pragma unroll
    for (int nt = 0; nt < 16; ++nt)
#pragma unroll
      for (int j = 0; j < 4; ++j) mx = fmaxf(mx, acc[nt][j]);
    mx = fmaxf(mx, __shfl_xor(mx, 16));
    mx = fmaxf(mx, __shfl_xor(mx, 32));
    float sum = 0.f;
#pragma unroll
    for (int nt = 0; nt < 16; ++nt) {
      bf16x4 pb;
#pragma unroll
      for (int j = 0; j < 4; ++j) {
        const float p = __expf((acc[nt][j] - mx) * 0.125f);
        pb[j] = (__bf16)p;
        sum += (float)pb[j];
      }
      const int byte = (lr * 512 + nt * 32 + kg * 8) ^ ((lr & 7) << 4);
      *(bf16x4*)(pw + byte) = pb;
    }
    sum += __shfl_xor(sum, 16);
    sum += __shfl_xor(sum, 32);
    const float inv = 1.f / sum;
    f32x4 oacc[4] = {};
#pragma unroll
    for (int kt = 0; kt < 8; ++kt) {
      const int pbyte = (lr * 512 + kt * 64 + kg * 16) ^ ((lr & 7) << 4);
      const bf16x8 bfrag = *(const bf16x8*)(pw + pbyte);
#pragma unroll
      for (int ct = 0; ct < 4; ++ct) {
        const int c = ct * 16 + lr;
        const int vbyte = (c * 512 + kt * 64 + kg * 16) ^ ((c & 7) << 4);
        const bf16x8 afrag = *(const bf16x8*)((char*)vt_lds + vbyte);
        oacc[ct] = __builtin_amdgcn_mfma_f32_16x16x32_bf16(afrag, bfrag, oacc[ct], 0, 0, 0);
      }
    }
    __bf16* orow = o + ((size_t)(t * N_DIM + q0 + lr)) * D_DIM + h * HD_DIM;
#pragma unroll
    for (int ct = 0; ct < 4; ++ct) {
      bf16x4 ov;
#pragma unroll
      for (int j = 0; j < 4; ++j) ov[j] = (__bf16)(oacc[ct][j] * inv);
      *(bf16x4*)(orow + ct * 16 + kg * 4) = ov;
    }
  }
}

// ---------------- CfC scan (fdot2): one WG/sequence, 768 threads -----------
// Frozen R11 config. OUTF32: 1 -> f32 out (final layer), 0 -> bf16 out (seq).
// addsrc is bf16 (seq) or null.
template <int OUTF32>
__global__ __launch_bounds__(768, 1) void scan_dot(const __bf16* __restrict__ P,
                                                   const _Float16* __restrict__ Whf,
                                                   const float* __restrict__ logtau,
                                                   const float* __restrict__ st,
                                                   const __bf16* __restrict__ addsrc,
                                                   void* __restrict__ out) {
  const int tid = threadIdx.x;
  const int n = blockIdx.x;
  const bool lead = tid < 256;  // wave-uniform (waves 0..3)

  __shared__ _Float16 h_buf[2][264];  // double-buffered h
  __shared__ float acc[776];          // a[jj] exchange
  __shared__ float dts[T_DIM];

  if (tid < T_DIM) dts[tid] = (tid == 0) ? st[0] : st[tid] - st[tid - 1];
  if (tid < 66) ((uint4*)h_buf)[tid] = (uint4){0, 0, 0, 0};

  // register-resident weight row jj = tid (128 f16x2)
  f16x2 wr[128];
  {
    const f16x2* wp = (const f16x2*)(Whf + (size_t)tid * 256);
#pragma unroll
    for (int i = 0; i < 128; ++i) wr[i] = wp[i];
  }
  const float tau = lead ? __expf(logtau[tid]) : 0.f;

  const unsigned short* Pp = (const unsigned short*)P + (size_t)n * 768 + tid;
  const size_t obase = (size_t)n * D_DIM + tid;
  const unsigned short* ap =
      (addsrc && lead) ? (const unsigned short*)addsrc + obase : nullptr;

  // distance-2 software pipeline on P (and addsrc), lead threads only
  unsigned short c1 = 0, c2 = 0, c3 = 0, n1 = 0, n2 = 0, n3 = 0;
  unsigned short av = 0, nav = 0;
  if (lead) {
    c1 = Pp[0]; c2 = Pp[256]; c3 = Pp[512];
    const unsigned short* Pn = Pp + (size_t)N_DIM * 768;
    n1 = Pn[0]; n2 = Pn[256]; n3 = Pn[512];
    if (ap) {
      av = ap[0];
      nav = ap[(size_t)N_DIM * D_DIM];
    }
  }
  __syncthreads();

  for (int t = 0; t < T_DIM; ++t) {
    // issue loads for t+2 (lead only); stay in flight across raw barriers
    unsigned short m1 = 0, m2 = 0, m3 = 0, mav = 0;
    if (lead && t + 2 < T_DIM) {
      const unsigned short* Pm = Pp + (size_t)(t + 2) * N_DIM * 768;
      m1 = Pm[0]; m2 = Pm[256]; m3 = Pm[512];
      if (ap) mav = ap[(size_t)(t + 2) * N_DIM * D_DIM];
    }

    // dot phase: h broadcast from buf[t&1], 128 fdot2
    const _Float16* hb = &h_buf[t & 1][0];
    float a = 0.f;
#pragma unroll
    for (int c = 0; c < 32; ++c) {
      const uint4 hu = *(const uint4*)(hb + c * 8);
      a = __builtin_amdgcn_fdot2(__builtin_bit_cast(f16x2, hu.x), wr[c * 4 + 0], a, false);
      a = __builtin_amdgcn_fdot2(__builtin_bit_cast(f16x2, hu.y), wr[c * 4 + 1], a, false);
      a = __builtin_amdgcn_fdot2(__builtin_bit_cast(f16x2, hu.z), wr[c * 4 + 2], a, false);
      a = __builtin_amdgcn_fdot2(__builtin_bit_cast(f16x2, hu.w), wr[c * 4 + 3], a, false);
    }
    acc[tid] = a;
    LDS_BAR();  // acc visible; this step's h reads done

    if (lead) {
      const float dt = dts[t];
      const float A1 = acc[tid] + bf_to_f(c1);
      const float A2 = acc[256 + tid] + bf_to_f(c2);
      const float A3 = acc[512 + tid] + bf_to_f(c3) - tau * dt;
      const float e1 = __expf(-2.f * fabsf(A1));
      const float f1 = copysignf((1.f - e1) / (1.f + e1), A1);
      const float e2 = __expf(-2.f * fabsf(A2));
      const float f2 = copysignf((1.f - e2) / (1.f + e2), A2);
      const float g = 1.f / (1.f + __expf(-A3));
      const float hn = g * f1 + (1.f - g) * f2;
      h_buf[(t + 1) & 1][tid] = (_Float16)hn;
      const float ov = hn + (ap ? bf_to_f(av) : 0.f);
      const size_t oi = obase + (size_t)t * N_DIM * D_DIM;
      if (OUTF32)
        ((float*)out)[oi] = ov;
      else
        ((__bf16*)out)[oi] = (__bf16)ov;
    }
    LDS_BAR();  // h_buf[next] visible for next step's dots

    c1 = n1; c2 = n2; c3 = n3; av = nav;
    n1 = m1; n2 = m2; n3 = m3; nav = mav;
  }
}

// ---------------- prep kernels ---------------------------------------------
__global__ void cvt_kernel(const float* __restrict__ src, __bf16* __restrict__ dst, int n) {
  const int i = blockIdx.x * 256 + threadIdx.x;
  if (i < n) dst[i] = (__bf16)src[i];
}

__global__ void pack_cell_kernel(const float* __restrict__ w1, const float* __restrict__ w2,
                                 const float* __restrict__ wt, __bf16* __restrict__ Wx,
                                 _Float16* __restrict__ Whf) {
  const int idx = blockIdx.x * 256 + threadIdx.x;  // over 3*768*256
  if (idx >= 3 * 768 * 256) return;
  const int l = idx / (768 * 256);
  const int r2 = idx - l * (768 * 256);
  const int jj = r2 >> 8;  // 0..767
  const int c = r2 & 255;
  const int m = jj >> 8;  // which matrix
  const int r = jj & 255;
  const float* src = (m == 0 ? w1 : (m == 1 ? w2 : wt)) + ((size_t)l * 256 + r) * 512;
  Wx[(size_t)l * (768 * 256) + (size_t)jj * 256 + c] = (__bf16)src[c];
  Whf[(size_t)l * (768 * 256) + (size_t)jj * 256 + c] = (_Float16)src[256 + c];
}

__global__ void bias_pack_kernel(const float* __restrict__ b1, const float* __restrict__ b2,
                                 const float* __restrict__ bt, const float* __restrict__ ff2b,
                                 const float* __restrict__ rw, const float* __restrict__ rb,
                                 const float* __restrict__ rn, float* __restrict__ bias768,
                                 float* __restrict__ ff2bias) {
  const int idx = blockIdx.x * 256 + threadIdx.x;
  if (idx < 3 * 768) {
    const int l = idx / 768, jj = idx % 768, m = jj >> 8, r = jj & 255;
    const float* s = (m == 0 ? b1 : (m == 1 ? b2 : bt));
    bias768[idx] = s[l * 256 + r];
  }
  if (idx < 256) ff2bias[idx] = ff2b[idx] + rw[idx] * rn[0] + rb[idx];
}

// ---------------------------------------------------------------------------
extern "C" void kernel_launch(void* const* d_in, const int* in_sizes, int n_in,
                              void* d_out, int out_size, void* d_ws, size_t ws_size,
                              hipStream_t stream) {
  (void)in_sizes; (void)n_in; (void)out_size; (void)ws_size;
  const float* spatial = (const float*)d_in[0];
  const float* re_norm = (const float*)d_in[1];
  const float* sensor_time = (const float*)d_in[2];
  const float* re_proj_w = (const float*)d_in[3];
  const float* re_proj_b = (const float*)d_in[4];
  const float* n1s = (const float*)d_in[5];
  const float* n1b = (const float*)d_in[6];
  const float* in_w = (const float*)d_in[7];
  const float* in_b = (const float*)d_in[8];
  const float* out_w = (const float*)d_in[9];
  const float* out_b = (const float*)d_in[10];
  const float* n2s = (const float*)d_in[11];
  const float* n2b = (const float*)d_in[12];
  const float* ff1_w = (const float*)d_in[13];
  const float* ff1_b = (const float*)d_in[14];
  const float* ff2_w = (const float*)d_in[15];
  const float* ff2_b = (const float*)d_in[16];
  const float* c1w = (const float*)d_in[17];
  const float* c1b = (const float*)d_in[18];
  const float* c2w = (const float*)d_in[19];
  const float* c2b = (const float*)d_in[20];
  const float* clt = (const float*)d_in[21];
  const float* ctw = (const float*)d_in[22];
  const float* ctb = (const float*)d_in[23];

  char* ws = (char*)d_ws;
  size_t off = 0;
  auto alloc = [&](size_t b) {
    char* p = ws + off;
    off = (off + b + 255) & ~(size_t)255;
    return p;
  };
  // persistent-per-layer buffers (residual streams now bf16)
  __bf16* seq = (__bf16*)alloc((size_t)TN * D_DIM * 2);    // 16.8 MB
  __bf16* xb = (__bf16*)alloc((size_t)TN * D_DIM * 2);     // 16.8 MB
  __bf16* yb = (__bf16*)alloc((size_t)TN * D_DIM * 2);     // 16.8 MB
  // big aliased region: qkv / ff1-out / P (disjoint live ranges)
  char* big = (char*)alloc((size_t)TN * 768 * 2);          // 50.3 MB
  __bf16* qkvb = (__bf16*)big;
  __bf16* gb = (__bf16*)big;
  __bf16* Pb = (__bf16*)big;
  // weights (~3.4 MB)
  __bf16* w_in = (__bf16*)alloc(768 * 256 * 2);
  __bf16* w_out = (__bf16*)alloc(256 * 256 * 2);
  __bf16* w_f1 = (__bf16*)alloc(512 * 256 * 2);
  __bf16* w_f2 = (__bf16*)alloc(256 * 512 * 2);
  __bf16* Wx = (__bf16*)alloc((size_t)3 * 768 * 256 * 2);
  _Float16* Whf = (_Float16*)alloc((size_t)3 * 768 * 256 * 2);
  float* b768 = (float*)alloc(3 * 768 * 4);
  float* f2bias = (float*)alloc(256 * 4);

  cvt_kernel<<<(768 * 256 + 255) / 256, 256, 0, stream>>>(in_w, w_in, 768 * 256);
  cvt_kernel<<<(256 * 256 + 255) / 256, 256, 0, stream>>>(out_w, w_out, 256 * 256);
  cvt_kernel<<<(512 * 256 + 255) / 256, 256, 0, stream>>>(ff1_w, w_f1, 512 * 256);
  cvt_kernel<<<(256 * 512 + 255) / 256, 256, 0, stream>>>(ff2_w, w_f2, 256 * 512);
  pack_cell_kernel<<<(3 * 768 * 256 + 255) / 256, 256, 0, stream>>>(c1w, c2w, ctw, Wx, Whf);
  bias_pack_kernel<<<9, 256, 0, stream>>>(c1b, c2b, ctb, ff2_b, re_proj_w, re_proj_b,
                                          re_norm, b768, f2bias);

  for (int l = 0; l < L_DIM; ++l) {
    // LN1
    if (l == 0)
      ln_kernel<float><<<TN / 4, 256, 0, stream>>>(spatial, n1s, n1b, yb);
    else
      ln_kernel<__bf16><<<TN / 4, 256, 0, stream>>>(seq, n1s, n1b, yb);
    // QKV
    gemm_tiled<0, 1, 0><<<dim3(TN / 128, 768 / 128), 256, 0, stream>>>(
        yb, w_in, in_b, nullptr, qkvb, TN, 768, 256);
    attn_mfma<<<dim3(T_DIM, H_DIM), 256, 0, stream>>>(qkvb, yb);
    // out-proj + residual (f32 spatial at l=0, bf16 seq after) -> xb (bf16)
    if (l == 0)
      gemm_tiled<1, 1, 0><<<dim3(TN / 128, 256 / 128), 256, 0, stream>>>(
          yb, w_out, out_b, spatial, xb, TN, 256, 256);
    else
      gemm_tiled<1, 1, 1><<<dim3(TN / 128, 256 / 128), 256, 0, stream>>>(
          yb, w_out, out_b, seq, xb, TN, 256, 256);
    // LN2
    ln_kernel<__bf16><<<TN / 4, 256, 0, stream>>>(xb, n2s, n2b, yb);
    // FF1 (SiLU) and FF2 (+residual xb)
    gemm_tiled<2, 1, 0><<<dim3(TN / 128, 512 / 128), 256, 0, stream>>>(
        yb, w_f1, ff1_b, nullptr, gb, TN, 512, 256);
    gemm_tiled<1, 1, 1><<<dim3(TN / 128, 256 / 128), 256, 0, stream>>>(
        gb, w_f2, f2bias, xb, yb, TN, 256, 512);
    // P pre-activations
    gemm_tiled<0, 1, 0><<<dim3(TN / 128, 768 / 128), 256, 0, stream>>>(
        yb, Wx + (size_t)l * 768 * 256, b768 + l * 768, nullptr, Pb, TN, 768, 256);
    // scan
    const __bf16* addp = (l == 0) ? nullptr : seq;
    if (l == 2)
      scan_dot<1><<<N_DIM, 768, 0, stream>>>(Pb, Whf + (size_t)l * 768 * 256,
                                             clt + l * 256, sensor_time, addp, d_out);
    else
      scan_dot<0><<<N_DIM, 768, 0, stream>>>(Pb, Whf + (size_t)l * 768 * 256,
                                             clt + l * 256, sensor_time, addp, seq);
  }
}

// Round 19
// 1100.188 us; speedup vs baseline: 1.1211x; 1.1211x over previous
//
#include <hip/hip_runtime.h>

// ---------------------------------------------------------------------------
// TemporalCfCEncoder: T=128, N=256, D=256, H=4 heads (hd=64), L=3 layers.
//  - GEMMs: 128x128 tile, A AND B LDS-staged (BK=64, raw barriers, load-ahead)
//    [R18's B-direct regressed: B loads at L2 latency on the critical path]
//  - attention: MFMA, S^T = K@Q^T direct from global; O^T = V^T@P^T swizzled LDS
//  - residual streams seq/xb in bf16 (f32 accumulate, one rounding per write)
//  - CfC scan: frozen R11 config (fdot2, 768 thr, L2-streamed weights).
// ---------------------------------------------------------------------------

#define T_DIM 128
#define N_DIM 256
#define D_DIM 256
#define H_DIM 4
#define HD_DIM 64
#define L_DIM 3
#define TN (T_DIM * N_DIM)

typedef __bf16 bf16x8 __attribute__((ext_vector_type(8)));
typedef __bf16 bf16x4 __attribute__((ext_vector_type(4)));
typedef float f32x4 __attribute__((ext_vector_type(4)));
typedef _Float16 f16x2 __attribute__((ext_vector_type(2)));

// LDS-only barrier: order ds ops across the WG without draining vmcnt.
#define LDS_BAR()                                            \
  do {                                                       \
    asm volatile("s_waitcnt lgkmcnt(0)" ::: "memory");       \
    __builtin_amdgcn_s_barrier();                            \
    __builtin_amdgcn_sched_barrier(0);                       \
  } while (0)

__device__ inline float wave_reduce_sum(float v) {
#pragma unroll
  for (int off = 32; off > 0; off >>= 1) v += __shfl_xor(v, off);
  return v;
}

__device__ inline float bf_to_f(unsigned short u) {
  return __uint_as_float((unsigned int)u << 16);
}

// ---------------- LN: one wave per row of 256 -> bf16 out ------------------
template <typename TI>
__global__ __launch_bounds__(256) void ln_kernel(const TI* __restrict__ x,
                                                 const float* __restrict__ sc,
                                                 const float* __restrict__ bi,
                                                 __bf16* __restrict__ y) {
  const int wid = threadIdx.x >> 6;
  const int lane = threadIdx.x & 63;
  const size_t row = (size_t)blockIdx.x * 4 + wid;
  float xv[4];
  if constexpr (__is_same(TI, float)) {
    const float4 v = *(const float4*)(x + row * D_DIM + lane * 4);
    xv[0] = v.x; xv[1] = v.y; xv[2] = v.z; xv[3] = v.w;
  } else {
    const bf16x4 v = *(const bf16x4*)(x + row * D_DIM + lane * 4);
#pragma unroll
    for (int i = 0; i < 4; ++i) xv[i] = (float)v[i];
  }
  float s = xv[0] + xv[1] + xv[2] + xv[3];
  float ss = xv[0] * xv[0] + xv[1] * xv[1] + xv[2] * xv[2] + xv[3] * xv[3];
  s = wave_reduce_sum(s);
  ss = wave_reduce_sum(ss);
  const float mean = s * (1.f / D_DIM);
  const float var = ss * (1.f / D_DIM) - mean * mean;
  const float r = rsqrtf(var + 1e-5f);
  const float4 scv = *(const float4*)(sc + lane * 4);
  const float4 biv = *(const float4*)(bi + lane * 4);
  bf16x4 ov;
  ov[0] = (__bf16)((xv[0] - mean) * r * scv.x + biv.x);
  ov[1] = (__bf16)((xv[1] - mean) * r * scv.y + biv.y);
  ov[2] = (__bf16)((xv[2] - mean) * r * scv.z + biv.z);
  ov[3] = (__bf16)((xv[3] - mean) * r * scv.w + biv.w);
  *(bf16x4*)(y + row * D_DIM + lane * 4) = ov;
}

// ---------------- Tiled GEMM: out = A[M,K] @ W[Nout,K]^T + bias (+epi) -----
// A and B staged in LDS (raw barriers, load-ahead). EPI: 0=bias,
// 1=bias+residual, 2=SiLU. OBF: bf16/f32 out. RBF: residual bf16(1)/f32(0).
template <int EPI, int OBF, int RBF>
__global__ __launch_bounds__(256) void gemm_tiled(const __bf16* __restrict__ A,
                                                  const __bf16* __restrict__ W,
                                                  const float* __restrict__ bias,
                                                  const void* __restrict__ R,
                                                  void* __restrict__ outv,
                                                  int M, int Nout, int K) {
  __shared__ __bf16 a_lds[128][72];
  __shared__ __bf16 b_lds[128][72];
  const int tid = threadIdx.x;
  const int w = tid >> 6, l = tid & 63;
  const int lr = l & 15, kg = l >> 4;
  const int wm = (w & 1) * 64, wn = (w >> 1) * 64;
  const int m0 = blockIdx.x * 128, n0 = blockIdx.y * 128;
  const int srow = tid >> 1, scol = (tid & 1) * 32;
  const __bf16* ag = A + (size_t)(m0 + srow) * K + scol;
  const __bf16* bg = W + (size_t)(n0 + srow) * K + scol;

  bf16x8 av[4], bv[4];
#pragma unroll
  for (int c = 0; c < 4; ++c) {
    av[c] = *(const bf16x8*)(ag + c * 8);
    bv[c] = *(const bf16x8*)(bg + c * 8);
  }

  f32x4 acc[4][4] = {};
  for (int k0 = 0; k0 < K; k0 += 64) {
    LDS_BAR();  // all waves finished reading LDS of previous k-step
#pragma unroll
    for (int c = 0; c < 4; ++c) {
      *(bf16x8*)&a_lds[srow][scol + c * 8] = av[c];
      *(bf16x8*)&b_lds[srow][scol + c * 8] = bv[c];
    }
    if (k0 + 64 < K) {
#pragma unroll
      for (int c = 0; c < 4; ++c) {
        av[c] = *(const bf16x8*)(ag + k0 + 64 + c * 8);
        bv[c] = *(const bf16x8*)(bg + k0 + 64 + c * 8);
      }
    }
    LDS_BAR();  // staging visible; k+1 loads remain in flight
#pragma unroll
    for (int ks = 0; ks < 2; ++ks) {
      bf16x8 af[4], bf[4];
#pragma unroll
      for (int mt = 0; mt < 4; ++mt)
        af[mt] = *(const bf16x8*)&a_lds[wm + mt * 16 + lr][ks * 32 + kg * 8];
#pragma unroll
      for (int nt = 0; nt < 4; ++nt)
        bf[nt] = *(const bf16x8*)&b_lds[wn + nt * 16 + lr][ks * 32 + kg * 8];
#pragma unroll
      for (int mt = 0; mt < 4; ++mt)
#pragma unroll
        for (int nt = 0; nt < 4; ++nt)
          acc[mt][nt] =
              __builtin_amdgcn_mfma_f32_16x16x32_bf16(af[mt], bf[nt], acc[mt][nt], 0, 0, 0);
    }
  }
  // epilogue: D[row=kg*4+j][col=lr] per 16x16 tile
#pragma unroll
  for (int nt = 0; nt < 4; ++nt) {
    const int col = n0 + wn + nt * 16 + lr;
    const float bvs = bias[col];
#pragma unroll
    for (int mt = 0; mt < 4; ++mt) {
#pragma unroll
      for (int j = 0; j < 4; ++j) {
        const int row = m0 + wm + mt * 16 + kg * 4 + j;
        float v = acc[mt][nt][j] + bvs;
        const size_t oi = (size_t)row * Nout + col;
        if (EPI == 1)
          v += RBF ? bf_to_f(((const unsigned short*)R)[oi]) : ((const float*)R)[oi];
        if (EPI == 2) v = v * (1.f / (1.f + __expf(-v)));
        if (OBF)
          ((__bf16*)outv)[oi] = (__bf16)v;
        else
          ((float*)outv)[oi] = v;
      }
    }
  }
}

// ---------------- Attention (MFMA): one WG per (t, head), 4 waves ----------
__global__ __launch_bounds__(256, 2) void attn_mfma(const __bf16* __restrict__ qkv,
                                                    __bf16* __restrict__ o) {
  const int t = blockIdx.x, h = blockIdx.y;
  const int tid = threadIdx.x;
  const int w = tid >> 6, l = tid & 63;
  const int lr = l & 15, kg = l >> 4;

  __shared__ __bf16 vt_lds[64 * 256];    // V^T [c][n], XOR-swizzled, 32KB
  __shared__ __bf16 p_lds[4][16 * 256];  // per-wave P [q][n], swizzled, 32KB

  {
    const __bf16* vrow = qkv + ((size_t)(t * N_DIM + tid)) * 768 + 512 + h * HD_DIM;
#pragma unroll
    for (int c8 = 0; c8 < 64; c8 += 8) {
      bf16x8 v = *(const bf16x8*)(vrow + c8);
#pragma unroll
      for (int i = 0; i < 8; ++i) {
        const int c = c8 + i;
        const int byte = (c * 512 + tid * 2) ^ ((c & 7) << 4);
        *(__bf16*)((char*)vt_lds + byte) = v[i];
      }
    }
  }
  __syncthreads();

  const __bf16* kbase = qkv + (size_t)t * N_DIM * 768 + 256 + h * HD_DIM;
  const __bf16* qbase = qkv + (size_t)t * N_DIM * 768 + h * HD_DIM;
  char* pw = (char*)&p_lds[w][0];

  for (int qt = 0; qt < 4; ++qt) {
    const int q0 = w * 64 + qt * 16;
    const bf16x8 qf0 = *(const bf16x8*)(qbase + (size_t)(q0 + lr) * 768 + kg * 8);
    const bf16x8 qf1 = *(const bf16x8*)(qbase + (size_t)(q0 + lr) * 768 + 32 + kg * 8);
    f32x4 acc[16];
#pragma unroll
    for (int nt = 0; nt < 16; ++nt) {
      const bf16x8 a0 = *(const bf16x8*)(kbase + (size_t)(nt * 16 + lr) * 768 + kg * 8);
      const bf16x8 a1 = *(const bf16x8*)(kbase + (size_t)(nt * 16 + lr) * 768 + 32 + kg * 8);
      f32x4 s = {};
      s = __builtin_amdgcn_mfma_f32_16x16x32_bf16(a0, qf0, s, 0, 0, 0);
      s = __builtin_amdgcn_mfma_f32_16x16x32_bf16(a1, qf1, s, 0, 0, 0);
      acc[nt] = s;
    }
    float mx = -3.0e38f;
#pragma unroll
    for (int nt = 0; nt < 16; ++nt)
#pragma unroll
      for (int j = 0; j < 4; ++j) mx = fmaxf(mx, acc[nt][j]);
    mx = fmaxf(mx, __shfl_xor(mx, 16));
    mx = fmaxf(mx, __shfl_xor(mx, 32));
    float sum = 0.f;
#pragma unroll
    for (int nt = 0; nt < 16; ++nt) {
      bf16x4 pb;
#pragma unroll
      for (int j = 0; j < 4; ++j) {
        const float p = __expf((acc[nt][j] - mx) * 0.125f);
        pb[j] = (__bf16)p;
        sum += (float)pb[j];
      }
      const int byte = (lr * 512 + nt * 32 + kg * 8) ^ ((lr & 7) << 4);
      *(bf16x4*)(pw + byte) = pb;
    }
    sum += __shfl_xor(sum, 16);
    sum += __shfl_xor(sum, 32);
    const float inv = 1.f / sum;
    f32x4 oacc[4] = {};
#pragma unroll
    for (int kt = 0; kt < 8; ++kt) {
      const int pbyte = (lr * 512 + kt * 64 + kg * 16) ^ ((lr & 7) << 4);
      const bf16x8 bfrag = *(const bf16x8*)(pw + pbyte);
#pragma unroll
      for (int ct = 0; ct < 4; ++ct) {
        const int c = ct * 16 + lr;
        const int vbyte = (c * 512 + kt * 64 + kg * 16) ^ ((c & 7) << 4);
        const bf16x8 afrag = *(const bf16x8*)((char*)vt_lds + vbyte);
        oacc[ct] = __builtin_amdgcn_mfma_f32_16x16x32_bf16(afrag, bfrag, oacc[ct], 0, 0, 0);
      }
    }
    __bf16* orow = o + ((size_t)(t * N_DIM + q0 + lr)) * D_DIM + h * HD_DIM;
#pragma unroll
    for (int ct = 0; ct < 4; ++ct) {
      bf16x4 ov;
#pragma unroll
      for (int j = 0; j < 4; ++j) ov[j] = (__bf16)(oacc[ct][j] * inv);
      *(bf16x4*)(orow + ct * 16 + kg * 4) = ov;
    }
  }
}

// ---------------- CfC scan (fdot2): one WG/sequence, 768 threads -----------
// Frozen R11 config. OUTF32: 1 -> f32 out (final layer), 0 -> bf16 out (seq).
template <int OUTF32>
__global__ __launch_bounds__(768, 1) void scan_dot(const __bf16* __restrict__ P,
                                                   const _Float16* __restrict__ Whf,
                                                   const float* __restrict__ logtau,
                                                   const float* __restrict__ st,
                                                   const __bf16* __restrict__ addsrc,
                                                   void* __restrict__ out) {
  const int tid = threadIdx.x;
  const int n = blockIdx.x;
  const bool lead = tid < 256;  // wave-uniform (waves 0..3)

  __shared__ _Float16 h_buf[2][264];  // double-buffered h
  __shared__ float acc[776];          // a[jj] exchange
  __shared__ float dts[T_DIM];

  if (tid < T_DIM) dts[tid] = (tid == 0) ? st[0] : st[tid] - st[tid - 1];
  if (tid < 66) ((uint4*)h_buf)[tid] = (uint4){0, 0, 0, 0};

  // register-resident weight row jj = tid (128 f16x2)
  f16x2 wr[128];
  {
    const f16x2* wp = (const f16x2*)(Whf + (size_t)tid * 256);
#pragma unroll
    for (int i = 0; i < 128; ++i) wr[i] = wp[i];
  }
  const float tau = lead ? __expf(logtau[tid]) : 0.f;

  const unsigned short* Pp = (const unsigned short*)P + (size_t)n * 768 + tid;
  const size_t obase = (size_t)n * D_DIM + tid;
  const unsigned short* ap =
      (addsrc && lead) ? (const unsigned short*)addsrc + obase : nullptr;

  // distance-2 software pipeline on P (and addsrc), lead threads only
  unsigned short c1 = 0, c2 = 0, c3 = 0, n1 = 0, n2 = 0, n3 = 0;
  unsigned short av = 0, nav = 0;
  if (lead) {
    c1 = Pp[0]; c2 = Pp[256]; c3 = Pp[512];
    const unsigned short* Pn = Pp + (size_t)N_DIM * 768;
    n1 = Pn[0]; n2 = Pn[256]; n3 = Pn[512];
    if (ap) {
      av = ap[0];
      nav = ap[(size_t)N_DIM * D_DIM];
    }
  }
  __syncthreads();

  for (int t = 0; t < T_DIM; ++t) {
    // issue loads for t+2 (lead only); stay in flight across raw barriers
    unsigned short m1 = 0, m2 = 0, m3 = 0, mav = 0;
    if (lead && t + 2 < T_DIM) {
      const unsigned short* Pm = Pp + (size_t)(t + 2) * N_DIM * 768;
      m1 = Pm[0]; m2 = Pm[256]; m3 = Pm[512];
      if (ap) mav = ap[(size_t)(t + 2) * N_DIM * D_DIM];
    }

    // dot phase: h broadcast from buf[t&1], 128 fdot2
    const _Float16* hb = &h_buf[t & 1][0];
    float a = 0.f;
#pragma unroll
    for (int c = 0; c < 32; ++c) {
      const uint4 hu = *(const uint4*)(hb + c * 8);
      a = __builtin_amdgcn_fdot2(__builtin_bit_cast(f16x2, hu.x), wr[c * 4 + 0], a, false);
      a = __builtin_amdgcn_fdot2(__builtin_bit_cast(f16x2, hu.y), wr[c * 4 + 1], a, false);
      a = __builtin_amdgcn_fdot2(__builtin_bit_cast(f16x2, hu.z), wr[c * 4 + 2], a, false);
      a = __builtin_amdgcn_fdot2(__builtin_bit_cast(f16x2, hu.w), wr[c * 4 + 3], a, false);
    }
    acc[tid] = a;
    LDS_BAR();  // acc visible; this step's h reads done

    if (lead) {
      const float dt = dts[t];
      const float A1 = acc[tid] + bf_to_f(c1);
      const float A2 = acc[256 + tid] + bf_to_f(c2);
      const float A3 = acc[512 + tid] + bf_to_f(c3) - tau * dt;
      const float e1 = __expf(-2.f * fabsf(A1));
      const float f1 = copysignf((1.f - e1) / (1.f + e1), A1);
      const float e2 = __expf(-2.f * fabsf(A2));
      const float f2 = copysignf((1.f - e2) / (1.f + e2), A2);
      const float g = 1.f / (1.f + __expf(-A3));
      const float hn = g * f1 + (1.f - g) * f2;
      h_buf[(t + 1) & 1][tid] = (_Float16)hn;
      const float ov = hn + (ap ? bf_to_f(av) : 0.f);
      const size_t oi = obase + (size_t)t * N_DIM * D_DIM;
      if (OUTF32)
        ((float*)out)[oi] = ov;
      else
        ((__bf16*)out)[oi] = (__bf16)ov;
    }
    LDS_BAR();  // h_buf[next] visible for next step's dots

    c1 = n1; c2 = n2; c3 = n3; av = nav;
    n1 = m1; n2 = m2; n3 = m3; nav = mav;
  }
}

// ---------------- prep kernels ---------------------------------------------
__global__ void cvt_kernel(const float* __restrict__ src, __bf16* __restrict__ dst, int n) {
  const int i = blockIdx.x * 256 + threadIdx.x;
  if (i < n) dst[i] = (__bf16)src[i];
}

__global__ void pack_cell_kernel(const float* __restrict__ w1, const float* __restrict__ w2,
                                 const float* __restrict__ wt, __bf16* __restrict__ Wx,
                                 _Float16* __restrict__ Whf) {
  const int idx = blockIdx.x * 256 + threadIdx.x;  // over 3*768*256
  if (idx >= 3 * 768 * 256) return;
  const int l = idx / (768 * 256);
  const int r2 = idx - l * (768 * 256);
  const int jj = r2 >> 8;  // 0..767
  const int c = r2 & 255;
  const int m = jj >> 8;  // which matrix
  const int r = jj & 255;
  const float* src = (m == 0 ? w1 : (m == 1 ? w2 : wt)) + ((size_t)l * 256 + r) * 512;
  Wx[(size_t)l * (768 * 256) + (size_t)jj * 256 + c] = (__bf16)src[c];
  Whf[(size_t)l * (768 * 256) + (size_t)jj * 256 + c] = (_Float16)src[256 + c];
}

__global__ void bias_pack_kernel(const float* __restrict__ b1, const float* __restrict__ b2,
                                 const float* __restrict__ bt, const float* __restrict__ ff2b,
                                 const float* __restrict__ rw, const float* __restrict__ rb,
                                 const float* __restrict__ rn, float* __restrict__ bias768,
                                 float* __restrict__ ff2bias) {
  const int idx = blockIdx.x * 256 + threadIdx.x;
  if (idx < 3 * 768) {
    const int l = idx / 768, jj = idx % 768, m = jj >> 8, r = jj & 255;
    const float* s = (m == 0 ? b1 : (m == 1 ? b2 : bt));
    bias768[idx] = s[l * 256 + r];
  }
  if (idx < 256) ff2bias[idx] = ff2b[idx] + rw[idx] * rn[0] + rb[idx];
}

// ---------------------------------------------------------------------------
extern "C" void kernel_launch(void* const* d_in, const int* in_sizes, int n_in,
                              void* d_out, int out_size, void* d_ws, size_t ws_size,
                              hipStream_t stream) {
  (void)in_sizes; (void)n_in; (void)out_size; (void)ws_size;
  const float* spatial = (const float*)d_in[0];
  const float* re_norm = (const float*)d_in[1];
  const float* sensor_time = (const float*)d_in[2];
  const float* re_proj_w = (const float*)d_in[3];
  const float* re_proj_b = (const float*)d_in[4];
  const float* n1s = (const float*)d_in[5];
  const float* n1b = (const float*)d_in[6];
  const float* in_w = (const float*)d_in[7];
  const float* in_b = (const float*)d_in[8];
  const float* out_w = (const float*)d_in[9];
  const float* out_b = (const float*)d_in[10];
  const float* n2s = (const float*)d_in[11];
  const float* n2b = (const float*)d_in[12];
  const float* ff1_w = (const float*)d_in[13];
  const float* ff1_b = (const float*)d_in[14];
  const float* ff2_w = (const float*)d_in[15];
  const float* ff2_b = (const float*)d_in[16];
  const float* c1w = (const float*)d_in[17];
  const float* c1b = (const float*)d_in[18];
  const float* c2w = (const float*)d_in[19];
  const float* c2b = (const float*)d_in[20];
  const float* clt = (const float*)d_in[21];
  const float* ctw = (const float*)d_in[22];
  const float* ctb = (const float*)d_in[23];

  char* ws = (char*)d_ws;
  size_t off = 0;
  auto alloc = [&](size_t b) {
    char* p = ws + off;
    off = (off + b + 255) & ~(size_t)255;
    return p;
  };
  // persistent-per-layer buffers (residual streams bf16)
  __bf16* seq = (__bf16*)alloc((size_t)TN * D_DIM * 2);    // 16.8 MB
  __bf16* xb = (__bf16*)alloc((size_t)TN * D_DIM * 2);     // 16.8 MB
  __bf16* yb = (__bf16*)alloc((size_t)TN * D_DIM * 2);     // 16.8 MB
  // big aliased region: qkv / ff1-out / P (disjoint live ranges)
  char* big = (char*)alloc((size_t)TN * 768 * 2);          // 50.3 MB
  __bf16* qkvb = (__bf16*)big;
  __bf16* gb = (__bf16*)big;
  __bf16* Pb = (__bf16*)big;
  // weights (~3.4 MB)
  __bf16* w_in = (__bf16*)alloc(768 * 256 * 2);
  __bf16* w_out = (__bf16*)alloc(256 * 256 * 2);
  __bf16* w_f1 = (__bf16*)alloc(512 * 256 * 2);
  __bf16* w_f2 = (__bf16*)alloc(256 * 512 * 2);
  __bf16* Wx = (__bf16*)alloc((size_t)3 * 768 * 256 * 2);
  _Float16* Whf = (_Float16*)alloc((size_t)3 * 768 * 256 * 2);
  float* b768 = (float*)alloc(3 * 768 * 4);
  float* f2bias = (float*)alloc(256 * 4);

  cvt_kernel<<<(768 * 256 + 255) / 256, 256, 0, stream>>>(in_w, w_in, 768 * 256);
  cvt_kernel<<<(256 * 256 + 255) / 256, 256, 0, stream>>>(out_w, w_out, 256 * 256);
  cvt_kernel<<<(512 * 256 + 255) / 256, 256, 0, stream>>>(ff1_w, w_f1, 512 * 256);
  cvt_kernel<<<(256 * 512 + 255) / 256, 256, 0, stream>>>(ff2_w, w_f2, 256 * 512);
  pack_cell_kernel<<<(3 * 768 * 256 + 255) / 256, 256, 0, stream>>>(c1w, c2w, ctw, Wx, Whf);
  bias_pack_kernel<<<9, 256, 0, stream>>>(c1b, c2b, ctb, ff2_b, re_proj_w, re_proj_b,
                                          re_norm, b768, f2bias);

  for (int l = 0; l < L_DIM; ++l) {
    // LN1
    if (l == 0)
      ln_kernel<float><<<TN / 4, 256, 0, stream>>>(spatial, n1s, n1b, yb);
    else
      ln_kernel<__bf16><<<TN / 4, 256, 0, stream>>>(seq, n1s, n1b, yb);
    // QKV
    gemm_tiled<0, 1, 0><<<dim3(TN / 128, 768 / 128), 256, 0, stream>>>(
        yb, w_in, in_b, nullptr, qkvb, TN, 768, 256);
    attn_mfma<<<dim3(T_DIM, H_DIM), 256, 0, stream>>>(qkvb, yb);
    // out-proj + residual (f32 spatial at l=0, bf16 seq after) -> xb (bf16)
    if (l == 0)
      gemm_tiled<1, 1, 0><<<dim3(TN / 128, 256 / 128), 256, 0, stream>>>(
          yb, w_out, out_b, spatial, xb, TN, 256, 256);
    else
      gemm_tiled<1, 1, 1><<<dim3(TN / 128, 256 / 128), 256, 0, stream>>>(
          yb, w_out, out_b, seq, xb, TN, 256, 256);
    // LN2
    ln_kernel<__bf16><<<TN / 4, 256, 0, stream>>>(xb, n2s, n2b, yb);
    // FF1 (SiLU) and FF2 (+residual xb)
    gemm_tiled<2, 1, 0><<<dim3(TN / 128, 512 / 128), 256, 0, stream>>>(
        yb, w_f1, ff1_b, nullptr, gb, TN, 512, 256);
    gemm_tiled<1, 1, 1><<<dim3(TN / 128, 256 / 128), 256, 0, stream>>>(
        gb, w_f2, f2bias, xb, yb, TN, 256, 512);
    // P pre-activations
    gemm_tiled<0, 1, 0><<<dim3(TN / 128, 768 / 128), 256, 0, stream>>>(
        yb, Wx + (size_t)l * 768 * 256, b768 + l * 768, nullptr, Pb, TN, 768, 256);
    // scan
    const __bf16* addp = (l == 0) ? nullptr : seq;
    if (l == 2)
      scan_dot<1><<<N_DIM, 768, 0, stream>>>(Pb, Whf + (size_t)l * 768 * 256,
                                             clt + l * 256, sensor_time, addp, d_out);
    else
      scan_dot<0><<<N_DIM, 768, 0, stream>>>(Pb, Whf + (size_t)l * 768 * 256,
                                             clt + l * 256, sensor_time, addp, seq);
  }
}